// Round 1
// baseline (2120.796 us; speedup 1.0000x reference)
//
#include <hip/hip_runtime.h>
#include <hip/hip_bf16.h>
#include <math.h>

typedef unsigned int u32;
typedef unsigned short u16;

#define B_    4
#define N_    131072
#define P_    (B_*N_)          // 524288
#define GX_   512
#define GY_   512
#define S_    (B_*GX_*GY_)     // 1048576
#define D_IN  25
#define H1_   32
#define H2_   64
#define DOUT_ 64
#define MAXPT 64
#define EPS_  1e-5f

__device__ __forceinline__ float bf2f(u16 h){ return __uint_as_float(((u32)h)<<16); }
__device__ __forceinline__ u16 f2bf(float f){ u32 b=__float_as_uint(f); u32 r=b+0x7FFFu+((b>>16)&1u); return (u16)(r>>16); }
// monotone float<->u32 order-preserving encoding (u32 0 == "untouched" sentinel)
__device__ __forceinline__ u32 encf(float f){ u32 b=__float_as_uint(f); return (b&0x80000000u)? ~b : (b|0x80000000u); }
__device__ __forceinline__ float decf(u32 e){ return __uint_as_float((e&0x80000000u)? (e&0x7FFFFFFFu) : ~e); }

__device__ __forceinline__ void unpack8(uint4 a, float* x){
  x[0]=bf2f((u16)(a.x&0xFFFFu)); x[1]=bf2f((u16)(a.x>>16));
  x[2]=bf2f((u16)(a.y&0xFFFFu)); x[3]=bf2f((u16)(a.y>>16));
  x[4]=bf2f((u16)(a.z&0xFFFFu)); x[5]=bf2f((u16)(a.z>>16));
  x[6]=bf2f((u16)(a.w&0xFFFFu)); x[7]=bf2f((u16)(a.w>>16));
}

// ---------------- pass A: build x0 (bf16, padded to 32), voxel rank, flags ----
__global__ __launch_bounds__(256) void passA(
    const float* __restrict__ fea, const int* __restrict__ xy, const int* __restrict__ lab,
    const float* __restrict__ emb, u32* __restrict__ cnt, u32* __restrict__ voxflag,
    u32* __restrict__ cntW, u16* __restrict__ x0)
{
  int p = blockIdx.x*256 + threadIdx.x;
  int b = p >> 17;                       // N = 2^17
  int ix = xy[2*p], iy = xy[2*p+1];
  u32 vox = ((u32)b<<18) + ((u32)ix<<9) + (u32)iy;
  u32 rank = atomicAdd(&cnt[vox], 1u);
  bool remain = rank < MAXPT;
  voxflag[p] = vox | (remain ? 0x80000000u : 0u);
  if (remain) atomicAdd(cntW, 1u);       // compiler wave-coalesces

  float v[32];
  #pragma unroll
  for (int k=0;k<9;k++) v[k] = fea[p*9+k];
  int l = lab[p];
  const float4* er = (const float4*)(emb + l*16);
  float4 e0=er[0], e1=er[1], e2=er[2], e3=er[3];
  v[9]=e0.x; v[10]=e0.y; v[11]=e0.z; v[12]=e0.w;
  v[13]=e1.x; v[14]=e1.y; v[15]=e1.z; v[16]=e1.w;
  v[17]=e2.x; v[18]=e2.y; v[19]=e2.z; v[20]=e2.w;
  v[21]=e3.x; v[22]=e3.y; v[23]=e3.z; v[24]=e3.w;
  #pragma unroll
  for (int k=25;k<32;k++) v[k]=0.f;
  if (!remain){
    #pragma unroll
    for (int k=0;k<32;k++) v[k]=0.f;     // zero rows don't pollute sums (divide by W)
  }
  u32 pk[16];
  #pragma unroll
  for (int k=0;k<16;k++) pk[k] = (u32)f2bf(v[2*k]) | ((u32)f2bf(v[2*k+1])<<16);
  uint4* dst = (uint4*)(x0 + (size_t)p*32);
  dst[0]=make_uint4(pk[0],pk[1],pk[2],pk[3]);
  dst[1]=make_uint4(pk[4],pk[5],pk[6],pk[7]);
  dst[2]=make_uint4(pk[8],pk[9],pk[10],pk[11]);
  dst[3]=make_uint4(pk[12],pk[13],pk[14],pk[15]);
}

// ---------------- column sums / sumsq of a P x C bf16 matrix -----------------
template<int C>
__global__ __launch_bounds__(256) void statsK(const u16* __restrict__ X,
                                              float* __restrict__ oSum, float* __restrict__ oSq)
{
  __shared__ float sS[C], sQ[C];
  int tid = threadIdx.x;
  for (int k=tid;k<C;k+=256){ sS[k]=0.f; sQ[k]=0.f; }
  __syncthreads();
  const int RPB = 256 / C;
  int c = tid % C, rg = tid / C;
  float s=0.f, q=0.f;
  for (int r = blockIdx.x*RPB + rg; r < P_; r += gridDim.x*RPB){
    float v = bf2f(X[(size_t)r*C + c]);
    s += v; q = fmaf(v,v,q);
  }
  atomicAdd(&sS[c], s); atomicAdd(&sQ[c], q);
  __syncthreads();
  for (int k=tid;k<C;k+=256){ atomicAdd(&oSum[k], sS[k]); atomicAdd(&oSq[k], sQ[k]); }
}

// ---------------- param kernels ----------------------------------------------
// p0: bn0 -> folded (transposed) layer-1 weights W1T[c*32+i], c1f[c]
__global__ void p0k(const float* __restrict__ sum0, const float* __restrict__ sq0,
                    const u32* __restrict__ cntW,
                    const float* __restrict__ g0, const float* __restrict__ b0,
                    const float* __restrict__ w1, const float* __restrict__ b1,
                    float* __restrict__ W1T, float* __restrict__ c1f)
{
  __shared__ float s0[D_IN], t0[D_IN];
  int tid = threadIdx.x; // 64
  float W = fmaxf((float)(*cntW), 1.f);
  if (tid < D_IN){
    float mu = sum0[tid]/W;
    float var = fmaxf(sq0[tid]/W - mu*mu, 0.f);
    float s = g0[tid]*rsqrtf(var+EPS_);
    s0[tid]=s; t0[tid]=b0[tid]-mu*s;
  }
  __syncthreads();
  if (tid < 32){
    float acc = b1[tid];
    #pragma unroll
    for (int i=0;i<D_IN;i++) acc = fmaf(t0[i], w1[i*32+tid], acc);
    c1f[tid] = acc;
    for (int i=0;i<32;i++) W1T[tid*32+i] = (i<D_IN)? s0[i]*w1[i*32+tid] : 0.f;
  }
}
// p1: bn1 affine (s1,t1) + transpose w2 -> w2T[c*32+i]
__global__ void p1k(const float* __restrict__ sum, const float* __restrict__ sq,
                    const u32* __restrict__ cntW,
                    const float* __restrict__ g, const float* __restrict__ bb,
                    const float* __restrict__ w2,
                    float* __restrict__ sOut, float* __restrict__ tOut, float* __restrict__ w2T)
{
  int tid = threadIdx.x; // 64
  if (tid < 32){
    float W = fmaxf((float)(*cntW),1.f);
    float mu = sum[tid]/W, var = fmaxf(sq[tid]/W-mu*mu,0.f);
    float s = g[tid]*rsqrtf(var+EPS_);
    sOut[tid]=s; tOut[tid]=bb[tid]-mu*s;
  }
  for (int i=0;i<32;i++) w2T[tid*32+i] = w2[i*64+tid];
}
// p2: bn2 affine (s2,t2) + transpose w3 -> w3T[c*64+i]
__global__ void p2k(const float* __restrict__ sum, const float* __restrict__ sq,
                    const u32* __restrict__ cntW,
                    const float* __restrict__ g, const float* __restrict__ bb,
                    const float* __restrict__ w3,
                    float* __restrict__ sOut, float* __restrict__ tOut, float* __restrict__ w3T)
{
  int tid = threadIdx.x; // 64
  float W = fmaxf((float)(*cntW),1.f);
  float mu = sum[tid]/W, var = fmaxf(sq[tid]/W-mu*mu,0.f);
  float s = g[tid]*rsqrtf(var+EPS_);
  sOut[tid]=s; tOut[tid]=bb[tid]-mu*s;
  for (int i=0;i<64;i++) w3T[tid*64+i] = w3[i*64+tid];
}

// ---------------- pass B: y1 = x0 @ W1T + c1f  (bf16 out) --------------------
__global__ __launch_bounds__(256) void passB(const u16* __restrict__ x0, const u32* __restrict__ voxflag,
    const float* __restrict__ W1T, const float* __restrict__ c1f, u16* __restrict__ y1)
{
  int p = blockIdx.x*256+threadIdx.x;
  const uint4* src = (const uint4*)(x0 + (size_t)p*32);
  float x[32];
  unpack8(src[0],x); unpack8(src[1],x+8); unpack8(src[2],x+16); unpack8(src[3],x+24);
  bool flag = (voxflag[p]>>31) != 0;
  u32 outp[16];
  #pragma unroll
  for (int cc=0; cc<16; cc++){
    int c0 = 2*cc;
    float a0=c1f[c0], a1=c1f[c0+1];
    #pragma unroll
    for (int i=0;i<32;i++){ a0=fmaf(x[i], W1T[c0*32+i], a0); a1=fmaf(x[i], W1T[(c0+1)*32+i], a1); }
    if(!flag){a0=0.f;a1=0.f;}
    outp[cc] = (u32)f2bf(a0) | ((u32)f2bf(a1)<<16);
  }
  uint4* dst = (uint4*)(y1 + (size_t)p*32);
  dst[0]=make_uint4(outp[0],outp[1],outp[2],outp[3]);
  dst[1]=make_uint4(outp[4],outp[5],outp[6],outp[7]);
  dst[2]=make_uint4(outp[8],outp[9],outp[10],outp[11]);
  dst[3]=make_uint4(outp[12],outp[13],outp[14],outp[15]);
}

// ---------------- pass C: x1 = relu(y1*s1+t1); y2 = x1 @ w2T + b2 ------------
__global__ __launch_bounds__(256) void passC(const u16* __restrict__ y1, const u32* __restrict__ voxflag,
    const float* __restrict__ s1, const float* __restrict__ t1,
    const float* __restrict__ w2T, const float* __restrict__ b2, u16* __restrict__ y2)
{
  int p = blockIdx.x*256+threadIdx.x;
  const uint4* src = (const uint4*)(y1 + (size_t)p*32);
  float x[32];
  unpack8(src[0],x); unpack8(src[1],x+8); unpack8(src[2],x+16); unpack8(src[3],x+24);
  bool flag = (voxflag[p]>>31) != 0;
  #pragma unroll
  for (int i=0;i<32;i++) x[i] = fmaxf(fmaf(x[i], s1[i], t1[i]), 0.f);
  u32 outp[32];
  for (int cc=0; cc<32; cc++){
    int c0 = 2*cc;
    float a0=b2[c0], a1=b2[c0+1];
    #pragma unroll
    for (int i=0;i<32;i++){ a0=fmaf(x[i], w2T[c0*32+i], a0); a1=fmaf(x[i], w2T[(c0+1)*32+i], a1); }
    if(!flag){a0=0.f;a1=0.f;}
    outp[cc] = (u32)f2bf(a0) | ((u32)f2bf(a1)<<16);
  }
  uint4* dst = (uint4*)(y2 + (size_t)p*64);
  #pragma unroll
  for (int q=0;q<8;q++) dst[q]=make_uint4(outp[4*q],outp[4*q+1],outp[4*q+2],outp[4*q+3]);
}

// ---------------- pass D: x2 = relu(y2*s2+t2); out3 = x2 @ w3T + b3; scatter --
__global__ __launch_bounds__(256) void passD(const u16* __restrict__ y2, const u32* __restrict__ voxflag,
    const float* __restrict__ s2, const float* __restrict__ t2,
    const float* __restrict__ w3T, const float* __restrict__ b3, u32* __restrict__ pooled)
{
  int p = blockIdx.x*256+threadIdx.x;
  u32 vf = voxflag[p];
  if (!(vf>>31)) return;
  const uint4* src = (const uint4*)(y2 + (size_t)p*64);
  float x[64];
  #pragma unroll
  for (int q=0;q<8;q++) unpack8(src[q], x+8*q);
  #pragma unroll
  for (int i=0;i<64;i++) x[i] = fmaxf(fmaf(x[i], s2[i], t2[i]), 0.f);
  u32 base = (vf & 0x7FFFFFFFu)*64u;
  for (int c=0;c<64;c++){
    float a=b3[c];
    #pragma unroll
    for (int i=0;i<64;i++) a = fmaf(x[i], w3T[c*64+i], a);
    atomicMax(&pooled[base+c], encf(a));
  }
}

// ---------------- fused decode + 3x3 max dilation + transpose ----------------
#define JT 64
#define IT 32
#define PITCH 67
__global__ __launch_bounds__(256) void dilate(const u32* __restrict__ pooled, float* __restrict__ out)
{
  __shared__ float vrow[3][66*PITCH];
  __shared__ float cm[66*PITCH];
  int j0 = blockIdx.x * JT;
  int i1 = blockIdx.y * IT;
  int b  = blockIdx.z;
  int tid = threadIdx.x;

  auto loadRow = [&](int i){
    int slot = (i+1)%3;  // i >= -1
    float* dst = vrow[slot];
    if (i < 0 || i >= 512){
      for (int e=tid; e<66*64; e+=256){ int jp=e>>6, c=e&63; dst[jp*PITCH+c] = -__builtin_inff(); }
    } else {
      const u32* rowp = pooled + ((size_t)(b*512 + i))*512*64;
      for (int e=tid; e<66*64; e+=256){
        int jp=e>>6, c=e&63; int jg = j0-1+jp;
        float val = -__builtin_inff();
        if (jg>=0 && jg<512){ u32 u = rowp[jg*64+c]; val = (u==0u)? 0.f : decf(u); }
        dst[jp*PITCH+c] = val;
      }
    }
  };

  loadRow(i1-1); loadRow(i1);
  for (int i=i1; i<i1+IT; i++){
    loadRow(i+1);
    __syncthreads();
    for (int e=tid; e<66*64; e+=256){
      int jp=e>>6, c=e&63; int a=jp*PITCH+c;
      cm[a] = fmaxf(fmaxf(vrow[0][a], vrow[1][a]), vrow[2][a]);
    }
    __syncthreads();
    int w = tid>>6, l = tid&63;
    #pragma unroll
    for (int k=0;k<16;k++){
      int c = w*16 + k;
      float m = fmaxf(fmaxf(cm[l*PITCH+c], cm[(l+1)*PITCH+c]), cm[(l+2)*PITCH+c]);
      out[(((size_t)b*64 + c)*512 + i)*512 + j0 + l] = m;
    }
    __syncthreads();
  }
}

// -----------------------------------------------------------------------------
extern "C" void kernel_launch(void* const* d_in, const int* in_sizes, int n_in,
                              void* d_out, int out_size, void* d_ws, size_t ws_size,
                              hipStream_t stream) {
  const float* fea  = (const float*)d_in[0];
  const int*   xy   = (const int*)d_in[1];
  const int*   lab  = (const int*)d_in[2];
  const float* emb  = (const float*)d_in[3];
  const float* bn0g = (const float*)d_in[4];
  const float* bn0b = (const float*)d_in[5];
  const float* w1   = (const float*)d_in[6];
  const float* b1   = (const float*)d_in[7];
  const float* bn1g = (const float*)d_in[8];
  const float* bn1b = (const float*)d_in[9];
  const float* w2   = (const float*)d_in[10];
  const float* b2   = (const float*)d_in[11];
  const float* bn2g = (const float*)d_in[12];
  const float* bn2b = (const float*)d_in[13];
  const float* w3   = (const float*)d_in[14];
  const float* b3   = (const float*)d_in[15];

  char* ws = (char*)d_ws;
  u32*  pooled  = (u32*)ws;                                        // S*64 u32 = 268.4 MB
  u32*  cnt     = (u32*)(ws + (size_t)S_*64*4);                    // S u32   = 4.2 MB
  u32*  voxflag = (u32*)(ws + (size_t)S_*64*4 + (size_t)S_*4);     // P u32   = 2.1 MB
  float* stats  = (float*)(ws + (size_t)S_*64*4 + (size_t)S_*4 + (size_t)P_*4);
  // stats layout (f32 idx): 0 sum0[32] | 32 sq0[32] | 64 sum1[32] | 96 sq1[32]
  //                         | 128 sum2[64] | 192 sq2[64] | 256 cntW(u32)
  u32*  cntW = (u32*)(stats + 256);
  float* c1f = stats + 260;       // 32
  float* s1  = stats + 292;       // 32
  float* t1  = stats + 324;       // 32
  float* s2  = stats + 356;       // 64
  float* t2  = stats + 420;       // 64
  float* W1T = stats + 512;       // 1024
  float* w2T = stats + 1536;      // 2048
  float* w3T = stats + 3584;      // 4096  (ends at 7680 f32)

  // activation scratch inside d_out (dead before dilate writes it)
  u16* x0 = (u16*)d_out;                                  // P*32 bf16 = 33.5 MB
  u16* y1 = (u16*)((char*)d_out + (size_t)P_*32*2);       // P*32 bf16
  u16* y2 = (u16*)((char*)d_out + (size_t)P_*64*2);       // P*64 bf16
  float* out = (float*)d_out;

  hipMemsetAsync(pooled, 0, (size_t)S_*64*4, stream);
  hipMemsetAsync(cnt,    0, (size_t)S_*4, stream);
  hipMemsetAsync(stats,  0, 2048, stream);   // stats + cntW (+ some param area, rewritten anyway)

  passA<<<P_/256, 256, 0, stream>>>(fea, xy, lab, emb, cnt, voxflag, cntW, x0);
  statsK<32><<<1024, 256, 0, stream>>>(x0, stats+0,  stats+32);
  p0k<<<1, 64, 0, stream>>>(stats+0, stats+32, cntW, bn0g, bn0b, w1, b1, W1T, c1f);
  passB<<<P_/256, 256, 0, stream>>>(x0, voxflag, W1T, c1f, y1);
  statsK<32><<<1024, 256, 0, stream>>>(y1, stats+64, stats+96);
  p1k<<<1, 64, 0, stream>>>(stats+64, stats+96, cntW, bn1g, bn1b, w2, s1, t1, w2T);
  passC<<<P_/256, 256, 0, stream>>>(y1, voxflag, s1, t1, w2T, b2, y2);
  statsK<64><<<1024, 256, 0, stream>>>(y2, stats+128, stats+192);
  p2k<<<1, 64, 0, stream>>>(stats+128, stats+192, cntW, bn2g, bn2b, w3, s2, t2, w3T);
  passD<<<P_/256, 256, 0, stream>>>(y2, voxflag, s2, t2, w3T, b3, pooled);
  dim3 dg(GX_/JT, GX_/IT, B_);
  dilate<<<dg, 256, 0, stream>>>(pooled, out);
}

// Round 3
// 657.089 us; speedup vs baseline: 3.2276x; 3.2276x over previous
//
#include <hip/hip_runtime.h>
#include <hip/hip_bf16.h>
#include <math.h>

typedef unsigned int u32;
typedef unsigned short u16;

#define B_    4
#define N_    131072
#define P_    (B_*N_)          // 524288
#define GX_   512
#define GY_   512
#define S_    (B_*GX_*GY_)     // 1048576
#define D_IN  25
#define MAXPT 64
#define EPS_  1e-5f

__device__ __forceinline__ float bf2f(u16 h){ return __uint_as_float(((u32)h)<<16); }
__device__ __forceinline__ u16 f2bf(float f){ u32 b=__float_as_uint(f); u32 r=b+0x7FFFu+((b>>16)&1u); return (u16)(r>>16); }

__device__ __forceinline__ void unpack8(uint4 a, float* x){
  x[0]=bf2f((u16)(a.x&0xFFFFu)); x[1]=bf2f((u16)(a.x>>16));
  x[2]=bf2f((u16)(a.y&0xFFFFu)); x[3]=bf2f((u16)(a.y>>16));
  x[4]=bf2f((u16)(a.z&0xFFFFu)); x[5]=bf2f((u16)(a.z>>16));
  x[6]=bf2f((u16)(a.w&0xFFFFu)); x[7]=bf2f((u16)(a.w>>16));
}

// ---------------- pass A: build x0 (bf16, padded to 32), voxel rank, flags ----
// voxflag bits: [19:0] vox, [25:20] rank (clamped 63), [31] remain
__global__ __launch_bounds__(256) void passA(
    const float* __restrict__ fea, const int* __restrict__ xy, const int* __restrict__ lab,
    const float* __restrict__ emb, u32* __restrict__ cnt, u32* __restrict__ voxflag,
    u32* __restrict__ cntW, u16* __restrict__ x0)
{
  int p = blockIdx.x*256 + threadIdx.x;
  int b = p >> 17;                       // N = 2^17
  int ix = xy[2*p], iy = xy[2*p+1];
  u32 vox = ((u32)b<<18) + ((u32)ix<<9) + (u32)iy;
  u32 rank = atomicAdd(&cnt[vox], 1u);
  bool remain = rank < MAXPT;
  voxflag[p] = vox | (min(rank,63u)<<20) | (remain ? 0x80000000u : 0u);
  if (remain) atomicAdd(cntW, 1u);       // compiler wave-coalesces

  float v[32];
  #pragma unroll
  for (int k=0;k<9;k++) v[k] = fea[p*9+k];
  int l = lab[p];
  const float4* er = (const float4*)(emb + l*16);
  float4 e0=er[0], e1=er[1], e2=er[2], e3=er[3];
  v[9]=e0.x; v[10]=e0.y; v[11]=e0.z; v[12]=e0.w;
  v[13]=e1.x; v[14]=e1.y; v[15]=e1.z; v[16]=e1.w;
  v[17]=e2.x; v[18]=e2.y; v[19]=e2.z; v[20]=e2.w;
  v[21]=e3.x; v[22]=e3.y; v[23]=e3.z; v[24]=e3.w;
  #pragma unroll
  for (int k=25;k<32;k++) v[k]=0.f;
  if (!remain){
    #pragma unroll
    for (int k=0;k<32;k++) v[k]=0.f;     // zero rows don't pollute sums (divide by W)
  }
  u32 pk[16];
  #pragma unroll
  for (int k=0;k<16;k++) pk[k] = (u32)f2bf(v[2*k]) | ((u32)f2bf(v[2*k+1])<<16);
  uint4* dst = (uint4*)(x0 + (size_t)p*32);
  dst[0]=make_uint4(pk[0],pk[1],pk[2],pk[3]);
  dst[1]=make_uint4(pk[4],pk[5],pk[6],pk[7]);
  dst[2]=make_uint4(pk[8],pk[9],pk[10],pk[11]);
  dst[3]=make_uint4(pk[12],pk[13],pk[14],pk[15]);
}

// ---------------- exclusive scan of clamped counts (3 small kernels) ---------
__global__ __launch_bounds__(256) void scan1(const u32* __restrict__ cnt,
                                             u32* __restrict__ scanned, u32* __restrict__ blockSum)
{
  __shared__ u32 ts[256];
  int tid = threadIdx.x;
  size_t base = (size_t)blockIdx.x*1024 + tid*4;
  uint4 c4 = *(const uint4*)(cnt + base);
  u32 c0=min(c4.x,64u), c1=min(c4.y,64u), c2=min(c4.z,64u), c3=min(c4.w,64u);
  u32 tsum = c0+c1+c2+c3;
  ts[tid]=tsum; __syncthreads();
  for (int off=1; off<256; off<<=1){
    u32 v = (tid>=off)? ts[tid-off] : 0u; __syncthreads();
    ts[tid]+=v; __syncthreads();
  }
  u32 ex = ts[tid]-tsum;
  uint4 o; o.x=ex; o.y=ex+c0; o.z=ex+c0+c1; o.w=ex+c0+c1+c2;
  *(uint4*)(scanned+base)=o;
  if (tid==255) blockSum[blockIdx.x]=ts[255];
}
__global__ __launch_bounds__(256) void scan2(u32* __restrict__ bs)
{
  __shared__ u32 ts[256];
  int tid=threadIdx.x;
  uint4 c4 = *(uint4*)(bs + tid*4);
  u32 tsum=c4.x+c4.y+c4.z+c4.w;
  ts[tid]=tsum; __syncthreads();
  for (int off=1;off<256;off<<=1){ u32 v=(tid>=off)?ts[tid-off]:0u; __syncthreads(); ts[tid]+=v; __syncthreads(); }
  u32 ex=ts[tid]-tsum;
  uint4 o; o.x=ex; o.y=ex+c4.x; o.z=ex+c4.x+c4.y; o.w=ex+c4.x+c4.y+c4.z;
  *(uint4*)(bs+tid*4)=o;
}
__global__ __launch_bounds__(256) void scan3(u32* __restrict__ scanned, const u32* __restrict__ bo)
{
  size_t base=(size_t)blockIdx.x*1024 + threadIdx.x*4;
  u32 add = bo[blockIdx.x];
  uint4 v=*(uint4*)(scanned+base);
  v.x+=add;v.y+=add;v.z+=add;v.w+=add;
  *(uint4*)(scanned+base)=v;
}
// scatter point indices into per-voxel segments (no atomics: rank from passA)
__global__ __launch_bounds__(256) void scatterK(const u32* __restrict__ voxflag,
    const u32* __restrict__ offsets, u32* __restrict__ sortedIdx)
{
  int p = blockIdx.x*256+threadIdx.x;
  u32 vf = voxflag[p];
  if (vf>>31){
    u32 vox = vf & 0xFFFFFu;
    u32 rank = (vf>>20)&63u;
    sortedIdx[offsets[vox]+rank] = (u32)p;
  }
}

// ---------------- column sums / sumsq of a P x C bf16 matrix -----------------
template<int C>
__global__ __launch_bounds__(256) void statsK(const u16* __restrict__ X,
                                              float* __restrict__ oSum, float* __restrict__ oSq)
{
  __shared__ float sS[C], sQ[C];
  int tid = threadIdx.x;
  for (int k=tid;k<C;k+=256){ sS[k]=0.f; sQ[k]=0.f; }
  __syncthreads();
  const int GPR = C/8;          // uint4 groups per row
  const int RPB = 256/GPR;      // rows per block iteration
  int g = tid % GPR, rg = tid / GPR;
  float s[8], q[8];
  #pragma unroll
  for (int j=0;j<8;j++){ s[j]=0.f; q[j]=0.f; }
  for (int r = blockIdx.x*RPB + rg; r < P_; r += gridDim.x*RPB){
    uint4 a = *(const uint4*)(X + (size_t)r*C + g*8);
    float x[8]; unpack8(a,x);
    #pragma unroll
    for (int j=0;j<8;j++){ s[j]+=x[j]; q[j]=fmaf(x[j],x[j],q[j]); }
  }
  #pragma unroll
  for (int j=0;j<8;j++){ atomicAdd(&sS[g*8+j], s[j]); atomicAdd(&sQ[g*8+j], q[j]); }
  __syncthreads();
  for (int k=tid;k<C;k+=256){ atomicAdd(&oSum[k], sS[k]); atomicAdd(&oSq[k], sQ[k]); }
}

// ---------------- param kernels ----------------------------------------------
__global__ void p0k(const float* __restrict__ sum0, const float* __restrict__ sq0,
                    const u32* __restrict__ cntW,
                    const float* __restrict__ g0, const float* __restrict__ b0,
                    const float* __restrict__ w1, const float* __restrict__ b1,
                    float* __restrict__ W1T, float* __restrict__ c1f)
{
  __shared__ float s0[D_IN], t0[D_IN];
  int tid = threadIdx.x; // 64
  float W = fmaxf((float)(*cntW), 1.f);
  if (tid < D_IN){
    float mu = sum0[tid]/W;
    float var = fmaxf(sq0[tid]/W - mu*mu, 0.f);
    float s = g0[tid]*rsqrtf(var+EPS_);
    s0[tid]=s; t0[tid]=b0[tid]-mu*s;
  }
  __syncthreads();
  if (tid < 32){
    float acc = b1[tid];
    #pragma unroll
    for (int i=0;i<D_IN;i++) acc = fmaf(t0[i], w1[i*32+tid], acc);
    c1f[tid] = acc;
    for (int i=0;i<32;i++) W1T[tid*32+i] = (i<D_IN)? s0[i]*w1[i*32+tid] : 0.f;
  }
}
__global__ void p1k(const float* __restrict__ sum, const float* __restrict__ sq,
                    const u32* __restrict__ cntW,
                    const float* __restrict__ g, const float* __restrict__ bb,
                    const float* __restrict__ w2,
                    float* __restrict__ sOut, float* __restrict__ tOut, float* __restrict__ w2T)
{
  int tid = threadIdx.x; // 64
  if (tid < 32){
    float W = fmaxf((float)(*cntW),1.f);
    float mu = sum[tid]/W, var = fmaxf(sq[tid]/W-mu*mu,0.f);
    float s = g[tid]*rsqrtf(var+EPS_);
    sOut[tid]=s; tOut[tid]=bb[tid]-mu*s;
  }
  for (int i=0;i<32;i++) w2T[tid*32+i] = w2[i*64+tid];
}
__global__ void p2k(const float* __restrict__ sum, const float* __restrict__ sq,
                    const u32* __restrict__ cntW,
                    const float* __restrict__ g, const float* __restrict__ bb,
                    const float* __restrict__ w3,
                    float* __restrict__ sOut, float* __restrict__ tOut, float* __restrict__ w3T)
{
  int tid = threadIdx.x; // 64
  float W = fmaxf((float)(*cntW),1.f);
  float mu = sum[tid]/W, var = fmaxf(sq[tid]/W-mu*mu,0.f);
  float s = g[tid]*rsqrtf(var+EPS_);
  sOut[tid]=s; tOut[tid]=bb[tid]-mu*s;
  for (int i=0;i<64;i++) w3T[tid*64+i] = w3[i*64+tid];
}

// ---------------- pass B: y1 = x0 @ W1T + c1f  (bf16 out) --------------------
__global__ __launch_bounds__(256) void passB(const u16* __restrict__ x0, const u32* __restrict__ voxflag,
    const float* __restrict__ W1T, const float* __restrict__ c1f, u16* __restrict__ y1)
{
  int p = blockIdx.x*256+threadIdx.x;
  const uint4* src = (const uint4*)(x0 + (size_t)p*32);
  float x[32];
  unpack8(src[0],x); unpack8(src[1],x+8); unpack8(src[2],x+16); unpack8(src[3],x+24);
  bool flag = (voxflag[p]>>31) != 0;
  u32 outp[16];
  #pragma unroll
  for (int cc=0; cc<16; cc++){
    int c0 = 2*cc;
    float a0=c1f[c0], a1=c1f[c0+1];
    #pragma unroll
    for (int i=0;i<32;i++){ a0=fmaf(x[i], W1T[c0*32+i], a0); a1=fmaf(x[i], W1T[(c0+1)*32+i], a1); }
    if(!flag){a0=0.f;a1=0.f;}
    outp[cc] = (u32)f2bf(a0) | ((u32)f2bf(a1)<<16);
  }
  uint4* dst = (uint4*)(y1 + (size_t)p*32);
  dst[0]=make_uint4(outp[0],outp[1],outp[2],outp[3]);
  dst[1]=make_uint4(outp[4],outp[5],outp[6],outp[7]);
  dst[2]=make_uint4(outp[8],outp[9],outp[10],outp[11]);
  dst[3]=make_uint4(outp[12],outp[13],outp[14],outp[15]);
}

// ---------------- pass C: x1 = relu(y1*s1+t1); y2 = x1 @ w2T + b2 ------------
__global__ __launch_bounds__(256) void passC(const u16* __restrict__ y1, const u32* __restrict__ voxflag,
    const float* __restrict__ s1, const float* __restrict__ t1,
    const float* __restrict__ w2T, const float* __restrict__ b2, u16* __restrict__ y2)
{
  int p = blockIdx.x*256+threadIdx.x;
  const uint4* src = (const uint4*)(y1 + (size_t)p*32);
  float x[32];
  unpack8(src[0],x); unpack8(src[1],x+8); unpack8(src[2],x+16); unpack8(src[3],x+24);
  bool flag = (voxflag[p]>>31) != 0;
  #pragma unroll
  for (int i=0;i<32;i++) x[i] = fmaxf(fmaf(x[i], s1[i], t1[i]), 0.f);
  u32 outp[32];
  for (int cc=0; cc<32; cc++){
    int c0 = 2*cc;
    float a0=b2[c0], a1=b2[c0+1];
    #pragma unroll
    for (int i=0;i<32;i++){ a0=fmaf(x[i], w2T[c0*32+i], a0); a1=fmaf(x[i], w2T[(c0+1)*32+i], a1); }
    if(!flag){a0=0.f;a1=0.f;}
    outp[cc] = (u32)f2bf(a0) | ((u32)f2bf(a1)<<16);
  }
  uint4* dst = (uint4*)(y2 + (size_t)p*64);
  #pragma unroll
  for (int q=0;q<8;q++) dst[q]=make_uint4(outp[4*q],outp[4*q+1],outp[4*q+2],outp[4*q+3]);
}

// ---------------- zpass: z = relu(y2*s2+t2) @ w3T + b3 (bf16, dense) ---------
__global__ __launch_bounds__(256) void zpass(const u16* __restrict__ y2,
    const float* __restrict__ s2, const float* __restrict__ t2,
    const float* __restrict__ w3T, const float* __restrict__ b3, u16* __restrict__ z)
{
  int p = blockIdx.x*256+threadIdx.x;
  const uint4* src = (const uint4*)(y2 + (size_t)p*64);
  float x[64];
  #pragma unroll
  for (int q=0;q<8;q++) unpack8(src[q], x+8*q);
  #pragma unroll
  for (int i=0;i<64;i++) x[i] = fmaxf(fmaf(x[i], s2[i], t2[i]), 0.f);
  u32 outp[32];
  for (int cc=0; cc<32; cc++){
    int c0 = 2*cc;
    float a0=b3[c0], a1=b3[c0+1];
    #pragma unroll
    for (int i=0;i<64;i++){ a0=fmaf(x[i], w3T[c0*64+i], a0); a1=fmaf(x[i], w3T[(c0+1)*64+i], a1); }
    outp[cc] = (u32)f2bf(a0) | ((u32)f2bf(a1)<<16);
  }
  uint4* dst = (uint4*)(z + (size_t)p*64);
  #pragma unroll
  for (int q=0;q<8;q++) dst[q]=make_uint4(outp[4*q],outp[4*q+1],outp[4*q+2],outp[4*q+3]);
}

// ---------------- pool: gather-max per voxel (8 threads/voxel, 8 ch each) ----
__global__ __launch_bounds__(256) void poolK(const u32* __restrict__ sortedIdx,
    const u32* __restrict__ offsets, const u32* __restrict__ cnt,
    const u16* __restrict__ z, u16* __restrict__ pooled)
{
  int t = blockIdx.x*256+threadIdx.x;
  int v = t>>3, sub = t&7;
  u32 n = min(cnt[v],64u);
  uint4* dst = (uint4*)(pooled + (size_t)v*64 + sub*8);
  if (n==0){ *dst = make_uint4(0,0,0,0); return; }
  u32 st = offsets[v];
  float m[8];
  #pragma unroll
  for (int j=0;j<8;j++) m[j] = -__builtin_inff();
  for (u32 k=0;k<n;k++){
    u32 p = sortedIdx[st+k];
    uint4 a = *(const uint4*)(z + (size_t)p*64 + sub*8);
    float x[8]; unpack8(a,x);
    #pragma unroll
    for (int j=0;j<8;j++) m[j]=fmaxf(m[j],x[j]);
  }
  uint4 o;
  o.x = (u32)f2bf(m[0]) | ((u32)f2bf(m[1])<<16);
  o.y = (u32)f2bf(m[2]) | ((u32)f2bf(m[3])<<16);
  o.z = (u32)f2bf(m[4]) | ((u32)f2bf(m[5])<<16);
  o.w = (u32)f2bf(m[6]) | ((u32)f2bf(m[7])<<16);
  *dst = o;
}

// ---------------- fused 3x3 max dilation + transpose (bf16 pooled in) --------
#define JT 64
#define IT 32
#define PITCH 67
__global__ __launch_bounds__(256) void dilate(const u16* __restrict__ pooled, float* __restrict__ out)
{
  __shared__ float vrow[3][66*PITCH];
  __shared__ float cm[66*PITCH];
  int j0 = blockIdx.x * JT;
  int i1 = blockIdx.y * IT;
  int b  = blockIdx.z;
  int tid = threadIdx.x;

  auto loadRow = [&](int i){
    int slot = (i+1)%3;  // i >= -1
    float* dst = vrow[slot];
    if (i < 0 || i >= 512){
      for (int e=tid; e<66*8; e+=256){
        int jp=e>>3, c8=e&7; float* d=&dst[jp*PITCH+c8*8];
        #pragma unroll
        for (int j=0;j<8;j++) d[j] = -__builtin_inff();
      }
    } else {
      const u16* rowp = pooled + ((size_t)(b*512 + i))*512*64;
      for (int e=tid; e<66*8; e+=256){
        int jp=e>>3, c8=e&7; int jg = j0-1+jp;
        float x[8];
        if (jg>=0 && jg<512){
          uint4 a = *(const uint4*)(rowp + jg*64 + c8*8);
          unpack8(a,x);
        } else {
          #pragma unroll
          for (int j=0;j<8;j++) x[j] = -__builtin_inff();
        }
        float* d = &dst[jp*PITCH+c8*8];
        #pragma unroll
        for (int j=0;j<8;j++) d[j]=x[j];
      }
    }
  };

  loadRow(i1-1); loadRow(i1);
  for (int i=i1; i<i1+IT; i++){
    loadRow(i+1);
    __syncthreads();
    for (int e=tid; e<66*64; e+=256){
      int jp=e>>6, c=e&63; int a=jp*PITCH+c;
      cm[a] = fmaxf(fmaxf(vrow[0][a], vrow[1][a]), vrow[2][a]);
    }
    __syncthreads();
    int w = tid>>6, l = tid&63;
    #pragma unroll
    for (int k=0;k<16;k++){
      int c = w*16 + k;
      float m = fmaxf(fmaxf(cm[l*PITCH+c], cm[(l+1)*PITCH+c]), cm[(l+2)*PITCH+c]);
      out[(((size_t)b*64 + c)*512 + i)*512 + j0 + l] = m;
    }
    __syncthreads();
  }
}

// -----------------------------------------------------------------------------
extern "C" void kernel_launch(void* const* d_in, const int* in_sizes, int n_in,
                              void* d_out, int out_size, void* d_ws, size_t ws_size,
                              hipStream_t stream) {
  const float* fea  = (const float*)d_in[0];
  const int*   xy   = (const int*)d_in[1];
  const int*   lab  = (const int*)d_in[2];
  const float* emb  = (const float*)d_in[3];
  const float* bn0g = (const float*)d_in[4];
  const float* bn0b = (const float*)d_in[5];
  const float* w1   = (const float*)d_in[6];
  const float* b1   = (const float*)d_in[7];
  const float* bn1g = (const float*)d_in[8];
  const float* bn1b = (const float*)d_in[9];
  const float* w2   = (const float*)d_in[10];
  const float* b2   = (const float*)d_in[11];
  const float* bn2g = (const float*)d_in[12];
  const float* bn2b = (const float*)d_in[13];
  const float* w3   = (const float*)d_in[14];
  const float* b3   = (const float*)d_in[15];

  char* ws = (char*)d_ws;
  size_t off = 0;
  u16*  z       = (u16*)(ws + off); off += (size_t)P_*64*2;   // 67.1 MB
  u16*  pooled  = (u16*)(ws + off); off += (size_t)S_*64*2;   // 134.2 MB
  u32*  cnt     = (u32*)(ws + off); off += (size_t)S_*4;      // 4.2 MB
  u32*  offsets = (u32*)(ws + off); off += (size_t)S_*4;      // 4.2 MB
  u32*  voxflag = (u32*)(ws + off); off += (size_t)P_*4;      // 2.1 MB
  u32*  sortedIdx=(u32*)(ws + off); off += (size_t)P_*4;      // 2.1 MB
  u32*  blockSum= (u32*)(ws + off); off += 4096;
  float* stats  = (float*)(ws + off);
  // stats layout (f32 idx): 0 sum0[32] | 32 sq0[32] | 64 sum1[32] | 96 sq1[32]
  //                         | 128 sum2[64] | 192 sq2[64] | 256 cntW
  u32*  cntW = (u32*)(stats + 256);
  float* c1f = stats + 260;
  float* s1  = stats + 292;
  float* t1  = stats + 324;
  float* s2  = stats + 356;
  float* t2  = stats + 420;
  float* W1T = stats + 512;       // 1024
  float* w2T = stats + 1536;      // 2048
  float* w3T = stats + 3584;      // 4096

  // activation scratch inside d_out (dead before dilate writes it)
  u16* x0 = (u16*)d_out;                                  // P*32 bf16
  u16* y1 = (u16*)((char*)d_out + (size_t)P_*32*2);       // P*32 bf16
  u16* y2 = (u16*)((char*)d_out + (size_t)P_*64*2);       // P*64 bf16
  float* out = (float*)d_out;

  hipMemsetAsync(cnt,   0, (size_t)S_*4, stream);
  hipMemsetAsync(stats, 0, 2048, stream);

  passA<<<P_/256, 256, 0, stream>>>(fea, xy, lab, emb, cnt, voxflag, cntW, x0);
  // counting-sort infrastructure (no atomics beyond passA's rank counters)
  scan1<<<S_/1024, 256, 0, stream>>>(cnt, offsets, blockSum);
  scan2<<<1, 256, 0, stream>>>(blockSum);
  scan3<<<S_/1024, 256, 0, stream>>>(offsets, blockSum);
  scatterK<<<P_/256, 256, 0, stream>>>(voxflag, offsets, sortedIdx);

  statsK<32><<<1024, 256, 0, stream>>>(x0, stats+0,  stats+32);
  p0k<<<1, 64, 0, stream>>>(stats+0, stats+32, cntW, bn0g, bn0b, w1, b1, W1T, c1f);
  passB<<<P_/256, 256, 0, stream>>>(x0, voxflag, W1T, c1f, y1);
  statsK<32><<<1024, 256, 0, stream>>>(y1, stats+64, stats+96);
  p1k<<<1, 64, 0, stream>>>(stats+64, stats+96, cntW, bn1g, bn1b, w2, s1, t1, w2T);
  passC<<<P_/256, 256, 0, stream>>>(y1, voxflag, s1, t1, w2T, b2, y2);
  statsK<64><<<1024, 256, 0, stream>>>(y2, stats+128, stats+192);
  p2k<<<1, 64, 0, stream>>>(stats+128, stats+192, cntW, bn2g, bn2b, w3, s2, t2, w3T);
  zpass<<<P_/256, 256, 0, stream>>>(y2, s2, t2, w3T, b3, z);
  poolK<<<(S_*8)/256, 256, 0, stream>>>(sortedIdx, offsets, cnt, z, pooled);
  dim3 dg(GX_/JT, GX_/IT, B_);
  dilate<<<dg, 256, 0, stream>>>(pooled, out);
}

// Round 4
// 595.806 us; speedup vs baseline: 3.5595x; 1.1029x over previous
//
#include <hip/hip_runtime.h>
#include <hip/hip_bf16.h>
#include <math.h>

typedef unsigned int u32;
typedef unsigned short u16;

#define B_    4
#define N_    131072
#define P_    (B_*N_)          // 524288
#define GX_   512
#define GY_   512
#define S_    (B_*GX_*GY_)     // 1048576
#define D_IN  25
#define MAXPT 64
#define EPS_  1e-5f

__device__ __forceinline__ float bf2f(u16 h){ return __uint_as_float(((u32)h)<<16); }
__device__ __forceinline__ u16 f2bf(float f){ u32 b=__float_as_uint(f); u32 r=b+0x7FFFu+((b>>16)&1u); return (u16)(r>>16); }

__device__ __forceinline__ void unpack8(uint4 a, float* x){
  x[0]=bf2f((u16)(a.x&0xFFFFu)); x[1]=bf2f((u16)(a.x>>16));
  x[2]=bf2f((u16)(a.y&0xFFFFu)); x[3]=bf2f((u16)(a.y>>16));
  x[4]=bf2f((u16)(a.z&0xFFFFu)); x[5]=bf2f((u16)(a.z>>16));
  x[6]=bf2f((u16)(a.w&0xFFFFu)); x[7]=bf2f((u16)(a.w>>16));
}

// build raw 25-dim feature (padded to 32) for point p
__device__ __forceinline__ void buildFeat(int p, const float* __restrict__ fea,
    const int* __restrict__ lab, const float* __restrict__ emb, float* v)
{
  #pragma unroll
  for (int k=0;k<9;k++) v[k] = fea[p*9+k];
  int l = lab[p];
  const float4* er = (const float4*)(emb + l*16);
  float4 e0=er[0], e1=er[1], e2=er[2], e3=er[3];
  v[9]=e0.x; v[10]=e0.y; v[11]=e0.z; v[12]=e0.w;
  v[13]=e1.x; v[14]=e1.y; v[15]=e1.z; v[16]=e1.w;
  v[17]=e2.x; v[18]=e2.y; v[19]=e2.z; v[20]=e2.w;
  v[21]=e3.x; v[22]=e3.y; v[23]=e3.z; v[24]=e3.w;
  #pragma unroll
  for (int k=25;k<32;k++) v[k]=0.f;
}

// block-wide column-sum/sumsq of 32 per-thread values via LDS transpose tile.
// tile: 256*33 floats. sS/sQ: LDS accumulators (caller-zeroed). Conflict-free:
// addr%32 == (tid+k)%32 on write, (r+c)%32 on read.
__device__ __forceinline__ void stats32(float* tile, float* sS, float* sQ,
                                        const float v[32], int tid)
{
  #pragma unroll
  for (int k=0;k<32;k++) tile[tid*33+k] = v[k];
  __syncthreads();
  int c = tid & 31, g = tid >> 5;         // 8 row-groups x 32 rows
  float s=0.f, q=0.f;
  #pragma unroll
  for (int r=0;r<32;r++){
    float x = tile[(g*32+r)*33 + c];
    s += x; q = fmaf(x,x,q);
  }
  atomicAdd(&sS[c], s); atomicAdd(&sQ[c], q);
  __syncthreads();   // tile reusable after this
}

// ---------------- pass A: voxel rank/flags + bn0 stats (no x0 write) ---------
// voxflag bits: [19:0] vox, [25:20] rank (clamped 63), [31] remain
__global__ __launch_bounds__(256) void passA(
    const float* __restrict__ fea, const int* __restrict__ xy, const int* __restrict__ lab,
    const float* __restrict__ emb, u32* __restrict__ cnt, u32* __restrict__ voxflag,
    u32* __restrict__ cntW, float* __restrict__ gSum, float* __restrict__ gSq)
{
  __shared__ float tile[256*33];
  __shared__ float sS[32], sQ[32];
  int tid = threadIdx.x;
  if (tid < 32){ sS[tid]=0.f; sQ[tid]=0.f; }
  int p = blockIdx.x*256 + tid;
  int b = p >> 17;                       // N = 2^17
  int ix = xy[2*p], iy = xy[2*p+1];
  u32 vox = ((u32)b<<18) + ((u32)ix<<9) + (u32)iy;
  u32 rank = atomicAdd(&cnt[vox], 1u);
  bool remain = rank < MAXPT;
  voxflag[p] = vox | (min(rank,63u)<<20) | (remain ? 0x80000000u : 0u);
  if (remain) atomicAdd(cntW, 1u);       // compiler wave-coalesces

  float v[32];
  buildFeat(p, fea, lab, emb, v);
  if (!remain){
    #pragma unroll
    for (int k=0;k<32;k++) v[k]=0.f;     // masked rows contribute zeros (divide by W)
  }
  __syncthreads();                        // sS/sQ init visible
  stats32(tile, sS, sQ, v, tid);
  if (tid < 32) atomicAdd(&gSum[tid], sS[tid]);
  else if (tid < 64) atomicAdd(&gSq[tid-32], sQ[tid-32]);
}

// ---------------- exclusive scan of clamped counts (3 small kernels) ---------
__global__ __launch_bounds__(256) void scan1(const u32* __restrict__ cnt,
                                             u32* __restrict__ scanned, u32* __restrict__ blockSum)
{
  __shared__ u32 ts[256];
  int tid = threadIdx.x;
  size_t base = (size_t)blockIdx.x*1024 + tid*4;
  uint4 c4 = *(const uint4*)(cnt + base);
  u32 c0=min(c4.x,64u), c1=min(c4.y,64u), c2=min(c4.z,64u), c3=min(c4.w,64u);
  u32 tsum = c0+c1+c2+c3;
  ts[tid]=tsum; __syncthreads();
  for (int off=1; off<256; off<<=1){
    u32 v = (tid>=off)? ts[tid-off] : 0u; __syncthreads();
    ts[tid]+=v; __syncthreads();
  }
  u32 ex = ts[tid]-tsum;
  uint4 o; o.x=ex; o.y=ex+c0; o.z=ex+c0+c1; o.w=ex+c0+c1+c2;
  *(uint4*)(scanned+base)=o;
  if (tid==255) blockSum[blockIdx.x]=ts[255];
}
__global__ __launch_bounds__(256) void scan2(u32* __restrict__ bs)
{
  __shared__ u32 ts[256];
  int tid=threadIdx.x;
  uint4 c4 = *(uint4*)(bs + tid*4);
  u32 tsum=c4.x+c4.y+c4.z+c4.w;
  ts[tid]=tsum; __syncthreads();
  for (int off=1;off<256;off<<=1){ u32 v=(tid>=off)?ts[tid-off]:0u; __syncthreads(); ts[tid]+=v; __syncthreads(); }
  u32 ex=ts[tid]-tsum;
  uint4 o; o.x=ex; o.y=ex+c4.x; o.z=ex+c4.x+c4.y; o.w=ex+c4.x+c4.y+c4.z;
  *(uint4*)(bs+tid*4)=o;
}
__global__ __launch_bounds__(256) void scan3(u32* __restrict__ scanned, const u32* __restrict__ bo)
{
  size_t base=(size_t)blockIdx.x*1024 + threadIdx.x*4;
  u32 add = bo[blockIdx.x];
  uint4 v=*(uint4*)(scanned+base);
  v.x+=add;v.y+=add;v.z+=add;v.w+=add;
  *(uint4*)(scanned+base)=v;
}

// ---------------- param kernels ----------------------------------------------
__global__ void p0k(const float* __restrict__ sum0, const float* __restrict__ sq0,
                    const u32* __restrict__ cntW,
                    const float* __restrict__ g0, const float* __restrict__ b0,
                    const float* __restrict__ w1, const float* __restrict__ b1,
                    float* __restrict__ W1T, float* __restrict__ c1f)
{
  __shared__ float s0[D_IN], t0[D_IN];
  int tid = threadIdx.x; // 64
  float W = fmaxf((float)(*cntW), 1.f);
  if (tid < D_IN){
    float mu = sum0[tid]/W;
    float var = fmaxf(sq0[tid]/W - mu*mu, 0.f);
    float s = g0[tid]*rsqrtf(var+EPS_);
    s0[tid]=s; t0[tid]=b0[tid]-mu*s;
  }
  __syncthreads();
  if (tid < 32){
    float acc = b1[tid];
    #pragma unroll
    for (int i=0;i<D_IN;i++) acc = fmaf(t0[i], w1[i*32+tid], acc);
    c1f[tid] = acc;
    for (int i=0;i<32;i++) W1T[tid*32+i] = (i<D_IN)? s0[i]*w1[i*32+tid] : 0.f;
  }
}
__global__ void p1k(const float* __restrict__ sum, const float* __restrict__ sq,
                    const u32* __restrict__ cntW,
                    const float* __restrict__ g, const float* __restrict__ bb,
                    const float* __restrict__ w2,
                    float* __restrict__ sOut, float* __restrict__ tOut, float* __restrict__ w2T)
{
  int tid = threadIdx.x; // 64
  if (tid < 32){
    float W = fmaxf((float)(*cntW),1.f);
    float mu = sum[tid]/W, var = fmaxf(sq[tid]/W-mu*mu,0.f);
    float s = g[tid]*rsqrtf(var+EPS_);
    sOut[tid]=s; tOut[tid]=bb[tid]-mu*s;
  }
  for (int i=0;i<32;i++) w2T[tid*32+i] = w2[i*64+tid];
}
__global__ void p2k(const float* __restrict__ sum, const float* __restrict__ sq,
                    const u32* __restrict__ cntW,
                    const float* __restrict__ g, const float* __restrict__ bb,
                    const float* __restrict__ w3,
                    float* __restrict__ sOut, float* __restrict__ tOut, float* __restrict__ w3T)
{
  int tid = threadIdx.x; // 64
  float W = fmaxf((float)(*cntW),1.f);
  float mu = sum[tid]/W, var = fmaxf(sq[tid]/W-mu*mu,0.f);
  float s = g[tid]*rsqrtf(var+EPS_);
  sOut[tid]=s; tOut[tid]=bb[tid]-mu*s;
  for (int i=0;i<64;i++) w3T[tid*64+i] = w3[i*64+tid];
}

// ---------------- pass B: rebuild feat, y1 = x@W1T + c1f, + bn1 stats --------
__global__ __launch_bounds__(256) void passB(
    const float* __restrict__ fea, const int* __restrict__ lab, const float* __restrict__ emb,
    const u32* __restrict__ voxflag,
    const float* __restrict__ W1T, const float* __restrict__ c1f,
    u16* __restrict__ y1, float* __restrict__ gSum, float* __restrict__ gSq)
{
  __shared__ float tile[256*33];
  __shared__ float sS[32], sQ[32];
  int tid = threadIdx.x;
  if (tid < 32){ sS[tid]=0.f; sQ[tid]=0.f; }
  int p = blockIdx.x*256 + tid;
  float x[32];
  buildFeat(p, fea, lab, emb, x);
  bool flag = (voxflag[p]>>31) != 0;
  float a[32];
  u32 outp[16];
  #pragma unroll
  for (int cc=0; cc<16; cc++){
    int c0 = 2*cc;
    float a0=c1f[c0], a1=c1f[c0+1];
    #pragma unroll
    for (int i=0;i<32;i++){ a0=fmaf(x[i], W1T[c0*32+i], a0); a1=fmaf(x[i], W1T[(c0+1)*32+i], a1); }
    if(!flag){a0=0.f;a1=0.f;}
    a[c0]=a0; a[c0+1]=a1;
    outp[cc] = (u32)f2bf(a0) | ((u32)f2bf(a1)<<16);
  }
  uint4* dst = (uint4*)(y1 + (size_t)p*32);
  dst[0]=make_uint4(outp[0],outp[1],outp[2],outp[3]);
  dst[1]=make_uint4(outp[4],outp[5],outp[6],outp[7]);
  dst[2]=make_uint4(outp[8],outp[9],outp[10],outp[11]);
  dst[3]=make_uint4(outp[12],outp[13],outp[14],outp[15]);
  __syncthreads();
  stats32(tile, sS, sQ, a, tid);
  if (tid < 32) atomicAdd(&gSum[tid], sS[tid]);
  else if (tid < 64) atomicAdd(&gSq[tid-32], sQ[tid-32]);
}

// ---------------- pass C: x1 = relu(y1*s1+t1); y2 = x1@w2T + b2; + bn2 stats -
__global__ __launch_bounds__(256) void passC(const u16* __restrict__ y1, const u32* __restrict__ voxflag,
    const float* __restrict__ s1, const float* __restrict__ t1,
    const float* __restrict__ w2T, const float* __restrict__ b2, u16* __restrict__ y2,
    float* __restrict__ gSum, float* __restrict__ gSq)
{
  __shared__ float tile[256*33];
  __shared__ float sS[64], sQ[64];
  int tid = threadIdx.x;
  if (tid < 64){ sS[tid]=0.f; sQ[tid]=0.f; }
  int p = blockIdx.x*256+tid;
  const uint4* src = (const uint4*)(y1 + (size_t)p*32);
  float x[32];
  unpack8(src[0],x); unpack8(src[1],x+8); unpack8(src[2],x+16); unpack8(src[3],x+24);
  bool flag = (voxflag[p]>>31) != 0;
  #pragma unroll
  for (int i=0;i<32;i++) x[i] = fmaxf(fmaf(x[i], s1[i], t1[i]), 0.f);
  uint4* dst = (uint4*)(y2 + (size_t)p*64);
  __syncthreads();
  // two halves of 32 channels, each reusing the LDS tile
  #pragma unroll
  for (int h=0; h<2; h++){
    float a[32];
    u32 outp[16];
    #pragma unroll
    for (int cc=0; cc<16; cc++){
      int c0 = h*32 + 2*cc;
      float a0=b2[c0], a1=b2[c0+1];
      #pragma unroll
      for (int i=0;i<32;i++){ a0=fmaf(x[i], w2T[c0*32+i], a0); a1=fmaf(x[i], w2T[(c0+1)*32+i], a1); }
      if(!flag){a0=0.f;a1=0.f;}
      a[2*cc]=a0; a[2*cc+1]=a1;
      outp[cc] = (u32)f2bf(a0) | ((u32)f2bf(a1)<<16);
    }
    #pragma unroll
    for (int q=0;q<4;q++) dst[h*4+q]=make_uint4(outp[4*q],outp[4*q+1],outp[4*q+2],outp[4*q+3]);
    stats32(tile, sS+h*32, sQ+h*32, a, tid);
  }
  if (tid < 64) atomicAdd(&gSum[tid], sS[tid]);
  else if (tid < 128) atomicAdd(&gSq[tid-64], sQ[tid-64]);
}

// ---------------- zpassS: z_sorted[slot] = relu(y2*s2+t2)@w3T + b3 (bf16) ----
__global__ __launch_bounds__(256) void zpassS(const u16* __restrict__ y2,
    const u32* __restrict__ voxflag, const u32* __restrict__ offsets,
    const float* __restrict__ s2, const float* __restrict__ t2,
    const float* __restrict__ w3T, const float* __restrict__ b3, u16* __restrict__ z)
{
  int p = blockIdx.x*256+threadIdx.x;
  u32 vf = voxflag[p];
  if (!(vf>>31)) return;                       // masked points never pooled
  u32 vox = vf & 0xFFFFFu;
  u32 rank = (vf>>20)&63u;
  u32 slot = offsets[vox] + rank;
  const uint4* src = (const uint4*)(y2 + (size_t)p*64);
  float x[64];
  #pragma unroll
  for (int q=0;q<8;q++) unpack8(src[q], x+8*q);
  #pragma unroll
  for (int i=0;i<64;i++) x[i] = fmaxf(fmaf(x[i], s2[i], t2[i]), 0.f);
  u32 outp[32];
  for (int cc=0; cc<32; cc++){
    int c0 = 2*cc;
    float a0=b3[c0], a1=b3[c0+1];
    #pragma unroll
    for (int i=0;i<64;i++){ a0=fmaf(x[i], w3T[c0*64+i], a0); a1=fmaf(x[i], w3T[(c0+1)*64+i], a1); }
    outp[cc] = (u32)f2bf(a0) | ((u32)f2bf(a1)<<16);
  }
  uint4* dst = (uint4*)(z + (size_t)slot*64);
  #pragma unroll
  for (int q=0;q<8;q++) dst[q]=make_uint4(outp[4*q],outp[4*q+1],outp[4*q+2],outp[4*q+3]);
}

// ---------------- pool: sequential segment gather-max (8 thr/voxel) ----------
__global__ __launch_bounds__(256) void poolK(
    const u32* __restrict__ offsets, const u32* __restrict__ cnt,
    const u16* __restrict__ z, u16* __restrict__ pooled)
{
  int t = blockIdx.x*256+threadIdx.x;
  int v = t>>3, sub = t&7;
  u32 n = min(cnt[v],64u);
  uint4* dst = (uint4*)(pooled + (size_t)v*64 + sub*8);
  if (n==0){ *dst = make_uint4(0,0,0,0); return; }
  u32 st = offsets[v];
  float m[8];
  #pragma unroll
  for (int j=0;j<8;j++) m[j] = -__builtin_inff();
  for (u32 k=0;k<n;k++){
    uint4 a = *(const uint4*)(z + (size_t)(st+k)*64 + sub*8);
    float x[8]; unpack8(a,x);
    #pragma unroll
    for (int j=0;j<8;j++) m[j]=fmaxf(m[j],x[j]);
  }
  uint4 o;
  o.x = (u32)f2bf(m[0]) | ((u32)f2bf(m[1])<<16);
  o.y = (u32)f2bf(m[2]) | ((u32)f2bf(m[3])<<16);
  o.z = (u32)f2bf(m[4]) | ((u32)f2bf(m[5])<<16);
  o.w = (u32)f2bf(m[6]) | ((u32)f2bf(m[7])<<16);
  *dst = o;
}

// ---------------- fused 3x3 max dilation + transpose (bf16 pooled in) --------
#define JT 64
#define IT 32
#define PITCH 67
__global__ __launch_bounds__(256) void dilate(const u16* __restrict__ pooled, float* __restrict__ out)
{
  __shared__ float vrow[3][66*PITCH];
  __shared__ float cm[66*PITCH];
  int j0 = blockIdx.x * JT;
  int i1 = blockIdx.y * IT;
  int b  = blockIdx.z;
  int tid = threadIdx.x;

  auto loadRow = [&](int i){
    int slot = (i+1)%3;  // i >= -1
    float* dst = vrow[slot];
    if (i < 0 || i >= 512){
      for (int e=tid; e<66*8; e+=256){
        int jp=e>>3, c8=e&7; float* d=&dst[jp*PITCH+c8*8];
        #pragma unroll
        for (int j=0;j<8;j++) d[j] = -__builtin_inff();
      }
    } else {
      const u16* rowp = pooled + ((size_t)(b*512 + i))*512*64;
      for (int e=tid; e<66*8; e+=256){
        int jp=e>>3, c8=e&7; int jg = j0-1+jp;
        float x[8];
        if (jg>=0 && jg<512){
          uint4 a = *(const uint4*)(rowp + jg*64 + c8*8);
          unpack8(a,x);
        } else {
          #pragma unroll
          for (int j=0;j<8;j++) x[j] = -__builtin_inff();
        }
        float* d = &dst[jp*PITCH+c8*8];
        #pragma unroll
        for (int j=0;j<8;j++) d[j]=x[j];
      }
    }
  };

  loadRow(i1-1); loadRow(i1);
  for (int i=i1; i<i1+IT; i++){
    loadRow(i+1);
    __syncthreads();
    for (int e=tid; e<66*64; e+=256){
      int jp=e>>6, c=e&63; int a=jp*PITCH+c;
      cm[a] = fmaxf(fmaxf(vrow[0][a], vrow[1][a]), vrow[2][a]);
    }
    __syncthreads();
    int w = tid>>6, l = tid&63;
    #pragma unroll
    for (int k=0;k<16;k++){
      int c = w*16 + k;
      float m = fmaxf(fmaxf(cm[l*PITCH+c], cm[(l+1)*PITCH+c]), cm[(l+2)*PITCH+c]);
      out[(((size_t)b*64 + c)*512 + i)*512 + j0 + l] = m;
    }
    __syncthreads();
  }
}

// -----------------------------------------------------------------------------
extern "C" void kernel_launch(void* const* d_in, const int* in_sizes, int n_in,
                              void* d_out, int out_size, void* d_ws, size_t ws_size,
                              hipStream_t stream) {
  const float* fea  = (const float*)d_in[0];
  const int*   xy   = (const int*)d_in[1];
  const int*   lab  = (const int*)d_in[2];
  const float* emb  = (const float*)d_in[3];
  const float* bn0g = (const float*)d_in[4];
  const float* bn0b = (const float*)d_in[5];
  const float* w1   = (const float*)d_in[6];
  const float* b1   = (const float*)d_in[7];
  const float* bn1g = (const float*)d_in[8];
  const float* bn1b = (const float*)d_in[9];
  const float* w2   = (const float*)d_in[10];
  const float* b2   = (const float*)d_in[11];
  const float* bn2g = (const float*)d_in[12];
  const float* bn2b = (const float*)d_in[13];
  const float* w3   = (const float*)d_in[14];
  const float* b3   = (const float*)d_in[15];

  char* ws = (char*)d_ws;
  size_t off = 0;
  u16*  z       = (u16*)(ws + off); off += (size_t)P_*64*2;   // 67.1 MB (voxel-sorted)
  u16*  pooled  = (u16*)(ws + off); off += (size_t)S_*64*2;   // 134.2 MB
  u32*  cnt     = (u32*)(ws + off); off += (size_t)S_*4;      // 4.2 MB
  u32*  offsets = (u32*)(ws + off); off += (size_t)S_*4;      // 4.2 MB
  u32*  voxflag = (u32*)(ws + off); off += (size_t)P_*4;      // 2.1 MB
  u32*  blockSum= (u32*)(ws + off); off += 4096;
  float* stats  = (float*)(ws + off);
  // stats f32 idx: 0 sum0[32] | 32 sq0[32] | 64 sum1[32] | 96 sq1[32]
  //                | 128 sum2[64] | 192 sq2[64] | 256 cntW
  u32*  cntW = (u32*)(stats + 256);
  float* c1f = stats + 260;
  float* s1  = stats + 292;
  float* t1  = stats + 324;
  float* s2  = stats + 356;
  float* t2  = stats + 420;
  float* W1T = stats + 512;       // 1024
  float* w2T = stats + 1536;      // 2048
  float* w3T = stats + 3584;      // 4096

  // activation scratch inside d_out (dead before dilate writes it)
  u16* y1 = (u16*)d_out;                                  // P*32 bf16 = 33.5 MB
  u16* y2 = (u16*)((char*)d_out + (size_t)P_*32*2);       // P*64 bf16 = 67.1 MB
  float* out = (float*)d_out;

  hipMemsetAsync(cnt,   0, (size_t)S_*4, stream);
  hipMemsetAsync(stats, 0, 2048, stream);

  passA<<<P_/256, 256, 0, stream>>>(fea, xy, lab, emb, cnt, voxflag, cntW,
                                    stats+0, stats+32);
  scan1<<<S_/1024, 256, 0, stream>>>(cnt, offsets, blockSum);
  scan2<<<1, 256, 0, stream>>>(blockSum);
  scan3<<<S_/1024, 256, 0, stream>>>(offsets, blockSum);
  p0k<<<1, 64, 0, stream>>>(stats+0, stats+32, cntW, bn0g, bn0b, w1, b1, W1T, c1f);
  passB<<<P_/256, 256, 0, stream>>>(fea, lab, emb, voxflag, W1T, c1f, y1,
                                    stats+64, stats+96);
  p1k<<<1, 64, 0, stream>>>(stats+64, stats+96, cntW, bn1g, bn1b, w2, s1, t1, w2T);
  passC<<<P_/256, 256, 0, stream>>>(y1, voxflag, s1, t1, w2T, b2, y2,
                                    stats+128, stats+192);
  p2k<<<1, 64, 0, stream>>>(stats+128, stats+192, cntW, bn2g, bn2b, w3, s2, t2, w3T);
  zpassS<<<P_/256, 256, 0, stream>>>(y2, voxflag, offsets, s2, t2, w3T, b3, z);
  poolK<<<(S_*8)/256, 256, 0, stream>>>(offsets, cnt, z, pooled);
  dim3 dg(GX_/JT, GX_/IT, B_);
  dilate<<<dg, 256, 0, stream>>>(pooled, out);
}

// Round 5
// 564.723 us; speedup vs baseline: 3.7555x; 1.0550x over previous
//
#include <hip/hip_runtime.h>
#include <hip/hip_bf16.h>
#include <math.h>

typedef unsigned int u32;
typedef unsigned short u16;

#define B_    4
#define N_    131072
#define P_    (B_*N_)          // 524288
#define GX_   512
#define GY_   512
#define S_    (B_*GX_*GY_)     // 1048576
#define D_IN  25
#define MAXPT 64
#define EPS_  1e-5f

__device__ __forceinline__ float bf2f(u16 h){ return __uint_as_float(((u32)h)<<16); }
__device__ __forceinline__ u16 f2bf(float f){ u32 b=__float_as_uint(f); u32 r=b+0x7FFFu+((b>>16)&1u); return (u16)(r>>16); }

__device__ __forceinline__ void unpack8(uint4 a, float* x){
  x[0]=bf2f((u16)(a.x&0xFFFFu)); x[1]=bf2f((u16)(a.x>>16));
  x[2]=bf2f((u16)(a.y&0xFFFFu)); x[3]=bf2f((u16)(a.y>>16));
  x[4]=bf2f((u16)(a.z&0xFFFFu)); x[5]=bf2f((u16)(a.z>>16));
  x[6]=bf2f((u16)(a.w&0xFFFFu)); x[7]=bf2f((u16)(a.w>>16));
}

// build raw 25-dim feature (padded to 32) for point p
__device__ __forceinline__ void buildFeat(int p, const float* __restrict__ fea,
    const int* __restrict__ lab, const float* __restrict__ emb, float* v)
{
  #pragma unroll
  for (int k=0;k<9;k++) v[k] = fea[p*9+k];
  int l = lab[p];
  const float4* er = (const float4*)(emb + l*16);
  float4 e0=er[0], e1=er[1], e2=er[2], e3=er[3];
  v[9]=e0.x; v[10]=e0.y; v[11]=e0.z; v[12]=e0.w;
  v[13]=e1.x; v[14]=e1.y; v[15]=e1.z; v[16]=e1.w;
  v[17]=e2.x; v[18]=e2.y; v[19]=e2.z; v[20]=e2.w;
  v[21]=e3.x; v[22]=e3.y; v[23]=e3.z; v[24]=e3.w;
  #pragma unroll
  for (int k=25;k<32;k++) v[k]=0.f;
}

// block-wide column-sum/sumsq of 32 per-thread values via LDS transpose tile.
__device__ __forceinline__ void stats32(float* tile, float* sS, float* sQ,
                                        const float v[32], int tid)
{
  #pragma unroll
  for (int k=0;k<32;k++) tile[tid*33+k] = v[k];
  __syncthreads();
  int c = tid & 31, g = tid >> 5;         // 8 row-groups x 32 rows
  float s=0.f, q=0.f;
  #pragma unroll
  for (int r=0;r<32;r++){
    float x = tile[(g*32+r)*33 + c];
    s += x; q = fmaf(x,x,q);
  }
  atomicAdd(&sS[c], s); atomicAdd(&sQ[c], q);
  __syncthreads();   // tile reusable after this
}

// ---------------- zeroK: replaces pathologically slow tiny hipMemsetAsync ----
__global__ __launch_bounds__(256) void zeroK(u32* __restrict__ cnt, float* __restrict__ stats)
{
  int t = blockIdx.x*256 + threadIdx.x;
  ((uint4*)cnt)[t] = make_uint4(0,0,0,0);              // 1024 blocks cover S_ u32
  if (blockIdx.x == 0 && threadIdx.x < 128)
    ((uint4*)stats)[threadIdx.x] = make_uint4(0,0,0,0); // 512 f32
}

// ---------------- pass A: voxel rank/flags + bn0 stats -----------------------
// voxflag bits: [19:0] vox, [25:20] rank (clamped 63), [31] remain
__global__ __launch_bounds__(256) void passA(
    const float* __restrict__ fea, const int* __restrict__ xy, const int* __restrict__ lab,
    const float* __restrict__ emb, u32* __restrict__ cnt, u32* __restrict__ voxflag,
    u32* __restrict__ cntW, float* __restrict__ gSum, float* __restrict__ gSq)
{
  __shared__ float tile[256*33];
  __shared__ float sS[32], sQ[32];
  int tid = threadIdx.x;
  if (tid < 32){ sS[tid]=0.f; sQ[tid]=0.f; }
  int p = blockIdx.x*256 + tid;
  int b = p >> 17;                       // N = 2^17
  int ix = xy[2*p], iy = xy[2*p+1];
  u32 vox = ((u32)b<<18) + ((u32)ix<<9) + (u32)iy;
  u32 rank = atomicAdd(&cnt[vox], 1u);
  bool remain = rank < MAXPT;
  voxflag[p] = vox | (min(rank,63u)<<20) | (remain ? 0x80000000u : 0u);
  if (remain) atomicAdd(cntW, 1u);       // compiler wave-coalesces

  float v[32];
  buildFeat(p, fea, lab, emb, v);
  if (!remain){
    #pragma unroll
    for (int k=0;k<32;k++) v[k]=0.f;     // masked rows contribute zeros (divide by W)
  }
  __syncthreads();                        // sS/sQ init visible
  stats32(tile, sS, sQ, v, tid);
  if (tid < 32) atomicAdd(&gSum[tid], sS[tid]);
  else if (tid < 64) atomicAdd(&gSq[tid-32], sQ[tid-32]);
}

// ---------------- exclusive scan of clamped counts (3 small kernels) ---------
__global__ __launch_bounds__(256) void scan1(const u32* __restrict__ cnt,
                                             u32* __restrict__ scanned, u32* __restrict__ blockSum)
{
  __shared__ u32 ts[256];
  int tid = threadIdx.x;
  size_t base = (size_t)blockIdx.x*1024 + tid*4;
  uint4 c4 = *(const uint4*)(cnt + base);
  u32 c0=min(c4.x,64u), c1=min(c4.y,64u), c2=min(c4.z,64u), c3=min(c4.w,64u);
  u32 tsum = c0+c1+c2+c3;
  ts[tid]=tsum; __syncthreads();
  for (int off=1; off<256; off<<=1){
    u32 v = (tid>=off)? ts[tid-off] : 0u; __syncthreads();
    ts[tid]+=v; __syncthreads();
  }
  u32 ex = ts[tid]-tsum;
  uint4 o; o.x=ex; o.y=ex+c0; o.z=ex+c0+c1; o.w=ex+c0+c1+c2;
  *(uint4*)(scanned+base)=o;
  if (tid==255) blockSum[blockIdx.x]=ts[255];
}
__global__ __launch_bounds__(256) void scan2(u32* __restrict__ bs)
{
  __shared__ u32 ts[256];
  int tid=threadIdx.x;
  uint4 c4 = *(uint4*)(bs + tid*4);
  u32 tsum=c4.x+c4.y+c4.z+c4.w;
  ts[tid]=tsum; __syncthreads();
  for (int off=1;off<256;off<<=1){ u32 v=(tid>=off)?ts[tid-off]:0u; __syncthreads(); ts[tid]+=v; __syncthreads(); }
  u32 ex=ts[tid]-tsum;
  uint4 o; o.x=ex; o.y=ex+c4.x; o.z=ex+c4.x+c4.y; o.w=ex+c4.x+c4.y+c4.z;
  *(uint4*)(bs+tid*4)=o;
}
__global__ __launch_bounds__(256) void scan3(u32* __restrict__ scanned, const u32* __restrict__ bo)
{
  size_t base=(size_t)blockIdx.x*1024 + threadIdx.x*4;
  u32 add = bo[blockIdx.x];
  uint4 v=*(uint4*)(scanned+base);
  v.x+=add;v.y+=add;v.z+=add;v.w+=add;
  *(uint4*)(scanned+base)=v;
}

// ---------------- param kernels ----------------------------------------------
__global__ void p0k(const float* __restrict__ sum0, const float* __restrict__ sq0,
                    const u32* __restrict__ cntW,
                    const float* __restrict__ g0, const float* __restrict__ b0,
                    const float* __restrict__ w1, const float* __restrict__ b1,
                    float* __restrict__ W1T, float* __restrict__ c1f)
{
  __shared__ float s0[D_IN], t0[D_IN];
  int tid = threadIdx.x; // 64
  float W = fmaxf((float)(*cntW), 1.f);
  if (tid < D_IN){
    float mu = sum0[tid]/W;
    float var = fmaxf(sq0[tid]/W - mu*mu, 0.f);
    float s = g0[tid]*rsqrtf(var+EPS_);
    s0[tid]=s; t0[tid]=b0[tid]-mu*s;
  }
  __syncthreads();
  if (tid < 32){
    float acc = b1[tid];
    #pragma unroll
    for (int i=0;i<D_IN;i++) acc = fmaf(t0[i], w1[i*32+tid], acc);
    c1f[tid] = acc;
    for (int i=0;i<32;i++) W1T[tid*32+i] = (i<D_IN)? s0[i]*w1[i*32+tid] : 0.f;
  }
}
__global__ void p1k(const float* __restrict__ sum, const float* __restrict__ sq,
                    const u32* __restrict__ cntW,
                    const float* __restrict__ g, const float* __restrict__ bb,
                    const float* __restrict__ w2,
                    float* __restrict__ sOut, float* __restrict__ tOut, float* __restrict__ w2T)
{
  int tid = threadIdx.x; // 64
  if (tid < 32){
    float W = fmaxf((float)(*cntW),1.f);
    float mu = sum[tid]/W, var = fmaxf(sq[tid]/W-mu*mu,0.f);
    float s = g[tid]*rsqrtf(var+EPS_);
    sOut[tid]=s; tOut[tid]=bb[tid]-mu*s;
  }
  for (int i=0;i<32;i++) w2T[tid*32+i] = w2[i*64+tid];
}
__global__ void p2k(const float* __restrict__ sum, const float* __restrict__ sq,
                    const u32* __restrict__ cntW,
                    const float* __restrict__ g, const float* __restrict__ bb,
                    const float* __restrict__ w3,
                    float* __restrict__ sOut, float* __restrict__ tOut, float* __restrict__ w3T)
{
  int tid = threadIdx.x; // 64
  float W = fmaxf((float)(*cntW),1.f);
  float mu = sum[tid]/W, var = fmaxf(sq[tid]/W-mu*mu,0.f);
  float s = g[tid]*rsqrtf(var+EPS_);
  sOut[tid]=s; tOut[tid]=bb[tid]-mu*s;
  for (int i=0;i<64;i++) w3T[tid*64+i] = w3[i*64+tid];
}

// ---------------- pass B: rebuild feat, y1 = x@W1T + c1f, + bn1 stats --------
__global__ __launch_bounds__(256) void passB(
    const float* __restrict__ fea, const int* __restrict__ lab, const float* __restrict__ emb,
    const u32* __restrict__ voxflag,
    const float* __restrict__ W1T, const float* __restrict__ c1f,
    u16* __restrict__ y1, float* __restrict__ gSum, float* __restrict__ gSq)
{
  __shared__ float tile[256*33];
  __shared__ float sS[32], sQ[32];
  int tid = threadIdx.x;
  if (tid < 32){ sS[tid]=0.f; sQ[tid]=0.f; }
  int p = blockIdx.x*256 + tid;
  float x[32];
  buildFeat(p, fea, lab, emb, x);
  bool flag = (voxflag[p]>>31) != 0;
  float a[32];
  u32 outp[16];
  #pragma unroll
  for (int cc=0; cc<16; cc++){
    int c0 = 2*cc;
    float a0=c1f[c0], a1=c1f[c0+1];
    #pragma unroll
    for (int i=0;i<32;i++){ a0=fmaf(x[i], W1T[c0*32+i], a0); a1=fmaf(x[i], W1T[(c0+1)*32+i], a1); }
    if(!flag){a0=0.f;a1=0.f;}
    a[c0]=a0; a[c0+1]=a1;
    outp[cc] = (u32)f2bf(a0) | ((u32)f2bf(a1)<<16);
  }
  uint4* dst = (uint4*)(y1 + (size_t)p*32);
  dst[0]=make_uint4(outp[0],outp[1],outp[2],outp[3]);
  dst[1]=make_uint4(outp[4],outp[5],outp[6],outp[7]);
  dst[2]=make_uint4(outp[8],outp[9],outp[10],outp[11]);
  dst[3]=make_uint4(outp[12],outp[13],outp[14],outp[15]);
  __syncthreads();
  stats32(tile, sS, sQ, a, tid);
  if (tid < 32) atomicAdd(&gSum[tid], sS[tid]);
  else if (tid < 64) atomicAdd(&gSq[tid-32], sQ[tid-32]);
}

// ---------------- pass C: x1 = relu(y1*s1+t1); y2 = x1@w2T + b2; + bn2 stats -
__global__ __launch_bounds__(256) void passC(const u16* __restrict__ y1, const u32* __restrict__ voxflag,
    const float* __restrict__ s1, const float* __restrict__ t1,
    const float* __restrict__ w2T, const float* __restrict__ b2, u16* __restrict__ y2,
    float* __restrict__ gSum, float* __restrict__ gSq)
{
  __shared__ float tile[256*33];
  __shared__ float sS[64], sQ[64];
  int tid = threadIdx.x;
  if (tid < 64){ sS[tid]=0.f; sQ[tid]=0.f; }
  int p = blockIdx.x*256+tid;
  const uint4* src = (const uint4*)(y1 + (size_t)p*32);
  float x[32];
  unpack8(src[0],x); unpack8(src[1],x+8); unpack8(src[2],x+16); unpack8(src[3],x+24);
  bool flag = (voxflag[p]>>31) != 0;
  #pragma unroll
  for (int i=0;i<32;i++) x[i] = fmaxf(fmaf(x[i], s1[i], t1[i]), 0.f);
  uint4* dst = (uint4*)(y2 + (size_t)p*64);
  __syncthreads();
  #pragma unroll
  for (int h=0; h<2; h++){
    float a[32];
    u32 outp[16];
    #pragma unroll
    for (int cc=0; cc<16; cc++){
      int c0 = h*32 + 2*cc;
      float a0=b2[c0], a1=b2[c0+1];
      #pragma unroll
      for (int i=0;i<32;i++){ a0=fmaf(x[i], w2T[c0*32+i], a0); a1=fmaf(x[i], w2T[(c0+1)*32+i], a1); }
      if(!flag){a0=0.f;a1=0.f;}
      a[2*cc]=a0; a[2*cc+1]=a1;
      outp[cc] = (u32)f2bf(a0) | ((u32)f2bf(a1)<<16);
    }
    #pragma unroll
    for (int q=0;q<4;q++) dst[h*4+q]=make_uint4(outp[4*q],outp[4*q+1],outp[4*q+2],outp[4*q+3]);
    stats32(tile, sS+h*32, sQ+h*32, a, tid);
  }
  if (tid < 64) atomicAdd(&gSum[tid], sS[tid]);
  else if (tid < 128) atomicAdd(&gSq[tid-64], sQ[tid-64]);
}

// ---------------- zpassS: z_sorted[slot] = relu(y2*s2+t2)@w3T + b3 (bf16) ----
__global__ __launch_bounds__(256) void zpassS(const u16* __restrict__ y2,
    const u32* __restrict__ voxflag, const u32* __restrict__ offsets,
    const float* __restrict__ s2, const float* __restrict__ t2,
    const float* __restrict__ w3T, const float* __restrict__ b3, u16* __restrict__ z)
{
  int p = blockIdx.x*256+threadIdx.x;
  u32 vf = voxflag[p];
  if (!(vf>>31)) return;                       // masked points never pooled
  u32 vox = vf & 0xFFFFFu;
  u32 rank = (vf>>20)&63u;
  u32 slot = offsets[vox] + rank;
  const uint4* src = (const uint4*)(y2 + (size_t)p*64);
  float x[64];
  #pragma unroll
  for (int q=0;q<8;q++) unpack8(src[q], x+8*q);
  #pragma unroll
  for (int i=0;i<64;i++) x[i] = fmaxf(fmaf(x[i], s2[i], t2[i]), 0.f);
  u32 outp[32];
  for (int cc=0; cc<32; cc++){
    int c0 = 2*cc;
    float a0=b3[c0], a1=b3[c0+1];
    #pragma unroll
    for (int i=0;i<64;i++){ a0=fmaf(x[i], w3T[c0*64+i], a0); a1=fmaf(x[i], w3T[(c0+1)*64+i], a1); }
    outp[cc] = (u32)f2bf(a0) | ((u32)f2bf(a1)<<16);
  }
  uint4* dst = (uint4*)(z + (size_t)slot*64);
  #pragma unroll
  for (int q=0;q<8;q++) dst[q]=make_uint4(outp[4*q],outp[4*q+1],outp[4*q+2],outp[4*q+3]);
}

// ---------------- pool: sequential segment gather-max (8 thr/voxel) ----------
__global__ __launch_bounds__(256) void poolK(
    const u32* __restrict__ offsets, const u32* __restrict__ cnt,
    const u16* __restrict__ z, u16* __restrict__ pooled)
{
  int t = blockIdx.x*256+threadIdx.x;
  int v = t>>3, sub = t&7;
  u32 n = min(cnt[v],64u);
  uint4* dst = (uint4*)(pooled + (size_t)v*64 + sub*8);
  if (n==0){ *dst = make_uint4(0,0,0,0); return; }
  u32 st = offsets[v];
  float m[8];
  #pragma unroll
  for (int j=0;j<8;j++) m[j] = -__builtin_inff();
  for (u32 k=0;k<n;k++){
    uint4 a = *(const uint4*)(z + (size_t)(st+k)*64 + sub*8);
    float x[8]; unpack8(a,x);
    #pragma unroll
    for (int j=0;j<8;j++) m[j]=fmaxf(m[j],x[j]);
  }
  uint4 o;
  o.x = (u32)f2bf(m[0]) | ((u32)f2bf(m[1])<<16);
  o.y = (u32)f2bf(m[2]) | ((u32)f2bf(m[3])<<16);
  o.z = (u32)f2bf(m[4]) | ((u32)f2bf(m[5])<<16);
  o.w = (u32)f2bf(m[6]) | ((u32)f2bf(m[7])<<16);
  *dst = o;
}

// ---------------- dilate: 1-sync fused vertical+horizontal max + transpose ---
// grid (4 j-tiles, 512 i, 4 b), block 256. LDS: vm[130][65] f32 (pitch-65).
#define DJT 128
__global__ __launch_bounds__(256) void dilate(const u16* __restrict__ pooled, float* __restrict__ out)
{
  __shared__ float vm[130*65];
  int j0  = blockIdx.x * DJT;
  int i   = blockIdx.y;
  int b   = blockIdx.z;
  int tid = threadIdx.x;
  const float NINF = -__builtin_inff();

  // stage 1: vertical 3-max (rows i-1,i,i+1) -> LDS, 8 channels per unit
  for (int e8 = tid; e8 < 130*8; e8 += 256){
    int j_t = e8>>3, c8 = e8&7;
    int jg = j0 - 1 + j_t;
    float m[8];
    #pragma unroll
    for (int q=0;q<8;q++) m[q]=NINF;
    if (jg>=0 && jg<512){
      #pragma unroll
      for (int d=-1; d<=1; d++){
        int ig = i+d;
        if (ig>=0 && ig<512){
          uint4 a = *(const uint4*)(pooled + (((size_t)(b*512+ig)*512 + jg)*64) + c8*8);
          float x[8]; unpack8(a,x);
          #pragma unroll
          for (int q=0;q<8;q++) m[q]=fmaxf(m[q],x[q]);
        }
      }
    }
    float* dp = &vm[j_t*65 + c8*8];
    #pragma unroll
    for (int q=0;q<8;q++) dp[q]=m[q];
  }
  __syncthreads();

  // stage 2: horizontal 3-max + transpose; wave w covers channels w*16..w*16+15,
  // lane l covers j-pair (2l, 2l+1) -> contiguous 512B float2 stores per wave
  int w = tid>>6, l = tid&63;
  #pragma unroll
  for (int k=0;k<16;k++){
    int c = w*16 + k;
    float v0 = vm[(2*l  )*65 + c];
    float v1 = vm[(2*l+1)*65 + c];
    float v2 = vm[(2*l+2)*65 + c];
    float v3 = vm[(2*l+3)*65 + c];
    float2 o = make_float2(fmaxf(fmaxf(v0,v1),v2), fmaxf(fmaxf(v1,v2),v3));
    *(float2*)(out + (((size_t)(b*64+c)*512)+i)*512 + j0 + 2*l) = o;
  }
}

// -----------------------------------------------------------------------------
extern "C" void kernel_launch(void* const* d_in, const int* in_sizes, int n_in,
                              void* d_out, int out_size, void* d_ws, size_t ws_size,
                              hipStream_t stream) {
  const float* fea  = (const float*)d_in[0];
  const int*   xy   = (const int*)d_in[1];
  const int*   lab  = (const int*)d_in[2];
  const float* emb  = (const float*)d_in[3];
  const float* bn0g = (const float*)d_in[4];
  const float* bn0b = (const float*)d_in[5];
  const float* w1   = (const float*)d_in[6];
  const float* b1   = (const float*)d_in[7];
  const float* bn1g = (const float*)d_in[8];
  const float* bn1b = (const float*)d_in[9];
  const float* w2   = (const float*)d_in[10];
  const float* b2   = (const float*)d_in[11];
  const float* bn2g = (const float*)d_in[12];
  const float* bn2b = (const float*)d_in[13];
  const float* w3   = (const float*)d_in[14];
  const float* b3   = (const float*)d_in[15];

  char* ws = (char*)d_ws;
  size_t off = 0;
  u16*  z       = (u16*)(ws + off); off += (size_t)P_*64*2;   // 67.1 MB (voxel-sorted)
  u16*  pooled  = (u16*)(ws + off); off += (size_t)S_*64*2;   // 134.2 MB
  u32*  cnt     = (u32*)(ws + off); off += (size_t)S_*4;      // 4.2 MB
  u32*  offsets = (u32*)(ws + off); off += (size_t)S_*4;      // 4.2 MB
  u32*  voxflag = (u32*)(ws + off); off += (size_t)P_*4;      // 2.1 MB
  u32*  blockSum= (u32*)(ws + off); off += 4096;
  float* stats  = (float*)(ws + off);
  // stats f32 idx: 0 sum0[32] | 32 sq0[32] | 64 sum1[32] | 96 sq1[32]
  //                | 128 sum2[64] | 192 sq2[64] | 256 cntW
  u32*  cntW = (u32*)(stats + 256);
  float* c1f = stats + 260;
  float* s1  = stats + 292;
  float* t1  = stats + 324;
  float* s2  = stats + 356;
  float* t2  = stats + 420;
  float* W1T = stats + 512;       // 1024
  float* w2T = stats + 1536;      // 2048
  float* w3T = stats + 3584;      // 4096

  // activation scratch inside d_out (dead before dilate writes it)
  u16* y1 = (u16*)d_out;                                  // P*32 bf16 = 33.5 MB
  u16* y2 = (u16*)((char*)d_out + (size_t)P_*32*2);       // P*64 bf16 = 67.1 MB
  float* out = (float*)d_out;

  zeroK<<<S_/1024, 256, 0, stream>>>(cnt, stats);
  passA<<<P_/256, 256, 0, stream>>>(fea, xy, lab, emb, cnt, voxflag, cntW,
                                    stats+0, stats+32);
  scan1<<<S_/1024, 256, 0, stream>>>(cnt, offsets, blockSum);
  scan2<<<1, 256, 0, stream>>>(blockSum);
  scan3<<<S_/1024, 256, 0, stream>>>(offsets, blockSum);
  p0k<<<1, 64, 0, stream>>>(stats+0, stats+32, cntW, bn0g, bn0b, w1, b1, W1T, c1f);
  passB<<<P_/256, 256, 0, stream>>>(fea, lab, emb, voxflag, W1T, c1f, y1,
                                    stats+64, stats+96);
  p1k<<<1, 64, 0, stream>>>(stats+64, stats+96, cntW, bn1g, bn1b, w2, s1, t1, w2T);
  passC<<<P_/256, 256, 0, stream>>>(y1, voxflag, s1, t1, w2T, b2, y2,
                                    stats+128, stats+192);
  p2k<<<1, 64, 0, stream>>>(stats+128, stats+192, cntW, bn2g, bn2b, w3, s2, t2, w3T);
  zpassS<<<P_/256, 256, 0, stream>>>(y2, voxflag, offsets, s2, t2, w3T, b3, z);
  poolK<<<(S_*8)/256, 256, 0, stream>>>(offsets, cnt, z, pooled);
  dim3 dg(GX_/DJT, GX_, B_);
  dilate<<<dg, 256, 0, stream>>>(pooled, out);
}